// Round 3
// baseline (231.314 us; speedup 1.0000x reference)
//
#include <hip/hip_runtime.h>

#define N_NODES 50000
#define N_EDGES 800000
#define HID 64
#define N_LAYERS 3
#define N_GRAPHS 64
#define MAXDEG 64
#define FIXS 4096.0f
#define CNTSTRIDE 32   // 1 counter per 128B line (kept; cheap)

typedef unsigned int u32;
typedef unsigned short ushort_t;
typedef short bf16x8 __attribute__((ext_vector_type(8)));
typedef float f32x4 __attribute__((ext_vector_type(4)));

__device__ __forceinline__ ushort_t f2bf(float f) {
    unsigned int u = __builtin_bit_cast(unsigned int, f);
    unsigned int r = u + 0x7fffu + ((u >> 16) & 1u);   // RNE
    return (ushort_t)(r >> 16);
}
__device__ __forceinline__ float lo16(u32 u) { return __builtin_bit_cast(float, u << 16); }
__device__ __forceinline__ float hi16(u32 u) { return __builtin_bit_cast(float, u & 0xffff0000u); }

// Fused: [0,EB) edge pass (1 edge/thread); [EB,EB+CVT) x_in -> two bf16 half-planes;
// [.., +GB) batch boundary scan; last block: uv fold.
__global__ __launch_bounds__(256) void edge_cvt_uv_kernel(
        const int* __restrict__ src, const int* __restrict__ dst,
        const float* __restrict__ ea,
        int* __restrict__ cnt, u32* __restrict__ ell,
        const float* __restrict__ x_in,
        uint4* __restrict__ lo_plane, uint4* __restrict__ hi_plane,
        const int* __restrict__ batch, int* __restrict__ gstart,
        const float* __restrict__ edge_w, const float* __restrict__ edge_b,
        const float* __restrict__ node_w, float* __restrict__ uv,
        int edgeBlocks, int cvtBlocks, int gbBlocks) {
    int t = threadIdx.x;
    int b = (int)blockIdx.x;
    if (b < edgeBlocks) {
        int e = b * 256 + t;
        if (e >= N_EDGES) return;
        int d = dst[e];
        float fv = (ea[e] + 8.0f) * FIXS;          // ea~N(0,1): in (0, 65536)
        fv = fminf(fmaxf(fv, 0.0f), 65535.0f);
        u32 fx = __float2uint_rn(fv);
        int pos = atomicAdd(&cnt[(size_t)d * CNTSTRIDE], 1);
        if (pos < MAXDEG) ell[((size_t)d << 6) + pos] = (u32)src[e] | (fx << 16);
        return;
    }
    if (b < edgeBlocks + cvtBlocks) {              // x_in -> bf16 HALF-PLANES
        int i = (b - edgeBlocks) * 256 + t;        // one thread = 8 floats
        if (i < N_NODES * HID / 8) {
            const float4* p = (const float4*)(x_in + (size_t)i * 8);
            float4 a = p[0], c = p[1];
            uint4 o;
            o.x = (u32)f2bf(a.x) | ((u32)f2bf(a.y) << 16);
            o.y = (u32)f2bf(a.z) | ((u32)f2bf(a.w) << 16);
            o.z = (u32)f2bf(c.x) | ((u32)f2bf(c.y) << 16);
            o.w = (u32)f2bf(c.z) | ((u32)f2bf(c.w) << 16);
            int row = i >> 3, g = i & 7;           // 8 uint4 per 64-feat row, 4 per plane
            if (g < 4) lo_plane[(size_t)row * 4 + g]       = o;
            else       hi_plane[(size_t)row * 4 + (g - 4)] = o;
        }
        return;
    }
    if (b < edgeBlocks + cvtBlocks + gbBlocks) {   // graph boundary scan (batch sorted)
        int i = (b - edgeBlocks - cvtBlocks) * 256 + t;
        if (i >= N_NODES) return;
        int bi = batch[i];
        if (i == 0) {
            for (int g = 0; g <= bi; g++) gstart[g] = 0;
        } else {
            int bp = batch[i - 1];
            for (int g = bp + 1; g <= bi; g++) gstart[g] = i;
        }
        if (i == N_NODES - 1) {
            for (int g = bi + 1; g <= N_GRAPHS; g++) gstart[g] = N_NODES;
        }
        return;
    }
    // uv fold
    if (t >= N_LAYERS * HID) return;
    int l = t >> 6, hp = t & 63;
    const float* w2 = node_w + l * 2 * HID * HID + HID * HID + hp;
    float u = 0.f, v = 0.f;
    for (int h = 0; h < HID; h++) {
        float w = w2[h * HID];
        u += edge_w[l * HID + h] * w;
        v += edge_b[l * HID + h] * w;
    }
    uv[l * 2 * HID + hp]       = u;
    uv[l * 2 * HID + HID + hp] = v;
}

// Pass 1 of a layer: gather the LO half-plane (3.2MB working set -> fits 4MB XCD L2)
// and write the aggregated half-row as bf16 (aggLO [N][32]) — already in MFMA A-fragment
// layout. Split-K-4: wave w owns ELL slots w*4 + 16j.
__global__ __launch_bounds__(256) void agg_lo_kernel(
        const uint4* __restrict__ xplane, const u32* __restrict__ ell,
        const int* __restrict__ cnt, uint4* __restrict__ aggLO) {
    __shared__ float redA[3][64][9];   // 9-float stride: 2-way (free) on 32 banks
    int lane = threadIdx.x & 63;
    int w = threadIdx.x >> 6;             // 0..3
    int nodeBase = blockIdx.x * 16;
    int q = lane >> 4, n15 = lane & 15;
    int m = nodeBase + n15;
    int dg = cnt[(size_t)m * CNTSTRIDE]; if (dg > MAXDEG) dg = MAXDEG;
    int mx = dg;
#pragma unroll
    for (int off = 1; off < 16; off <<= 1) {
        int o = __shfl_xor(mx, off);
        mx = o > mx ? o : mx;
    }
    const uint4* erow4 = (const uint4*)(ell + ((size_t)m << 6));
    float accA[8] = {0,0,0,0,0,0,0,0};
    int base = w * 4;
    uint4 e4 = {0, 0, 0, 0};
    if (base < mx) e4 = erow4[base >> 2];
    for (; base < mx; base += 16) {
        int nbase = base + 16;
        uint4 e4n = {0, 0, 0, 0};
        if (nbase < mx) e4n = erow4[nbase >> 2];
        u32 ee[4] = {e4.x, e4.y, e4.z, e4.w};
        uint4 lo[4];
        float f[4];
#pragma unroll
        for (int k = 0; k < 4; k++) {              // issue all 4 row loads first
            bool v = (base + k) < dg;
            int s = v ? (int)(ee[k] & 0xffffu) : 0;
            lo[k] = xplane[(size_t)s * 4 + q];     // plane row = 4 uint4 (32 bf16)
            f[k] = v ? 1.0f : 0.0f;
        }
#pragma unroll
        for (int k = 0; k < 4; k++) {
            accA[0] += f[k] * lo16(lo[k].x); accA[1] += f[k] * hi16(lo[k].x);
            accA[2] += f[k] * lo16(lo[k].y); accA[3] += f[k] * hi16(lo[k].y);
            accA[4] += f[k] * lo16(lo[k].z); accA[5] += f[k] * hi16(lo[k].z);
            accA[6] += f[k] * lo16(lo[k].w); accA[7] += f[k] * hi16(lo[k].w);
        }
        e4 = e4n;
    }
    if (w != 0) {
#pragma unroll
        for (int j = 0; j < 8; j++) redA[w - 1][lane][j] = accA[j];
    }
    __syncthreads();
    if (w != 0) return;
#pragma unroll
    for (int p = 0; p < 3; p++)
#pragma unroll
        for (int j = 0; j < 8; j++) accA[j] += redA[p][lane][j];
    uint4 o;
    o.x = (u32)f2bf(accA[0]) | ((u32)f2bf(accA[1]) << 16);
    o.y = (u32)f2bf(accA[2]) | ((u32)f2bf(accA[3]) << 16);
    o.z = (u32)f2bf(accA[4]) | ((u32)f2bf(accA[5]) << 16);
    o.w = (u32)f2bf(accA[6]) | ((u32)f2bf(accA[7]) << 16);
    aggLO[(size_t)m * 4 + q] = o;                  // coalesced: block writes 1KB run
}

// Pass 2: gather the HI half-plane (3.2MB, L2-resident), fixed-point edge-attr sum,
// reload aggLO as af0, MFMA + epilogue. Writes next layer's planes (or fp32 xA).
__global__ __launch_bounds__(256) void agg_hi_mfma_kernel(
        const uint4* __restrict__ xplane, const uint4* __restrict__ aggLO,
        const u32* __restrict__ ell, const int* __restrict__ cnt,
        const float* __restrict__ W1, const float* __restrict__ node_b_l,
        const float* __restrict__ uv_l, float* __restrict__ sattr,
        int layer0, ushort_t* __restrict__ out_lo, ushort_t* __restrict__ out_hi,
        float* __restrict__ out_f32) {
    __shared__ float redB[3][64][9];
    __shared__ u32   redS[3][64];
    int lane = threadIdx.x & 63;
    int w = threadIdx.x >> 6;             // 0..3
    int nodeBase = blockIdx.x * 16;
    int q = lane >> 4, n15 = lane & 15;
    int m = nodeBase + n15;
    int dg = cnt[(size_t)m * CNTSTRIDE]; if (dg > MAXDEG) dg = MAXDEG;
    int mx = dg;
#pragma unroll
    for (int off = 1; off < 16; off <<= 1) {
        int o = __shfl_xor(mx, off);
        mx = o > mx ? o : mx;
    }
    const uint4* erow4 = (const uint4*)(ell + ((size_t)m << 6));
    float accB[8] = {0,0,0,0,0,0,0,0};
    u32 sfix = 0;
    int base = w * 4;
    uint4 e4 = {0, 0, 0, 0};
    if (base < mx) e4 = erow4[base >> 2];
    for (; base < mx; base += 16) {
        int nbase = base + 16;
        uint4 e4n = {0, 0, 0, 0};
        if (nbase < mx) e4n = erow4[nbase >> 2];
        u32 ee[4] = {e4.x, e4.y, e4.z, e4.w};
        uint4 hi[4];
        float f[4];
#pragma unroll
        for (int k = 0; k < 4; k++) {
            bool v = (base + k) < dg;
            u32 e = ee[k];
            sfix += v ? (e >> 16) : 0u;
            int s = v ? (int)(e & 0xffffu) : 0;
            hi[k] = xplane[(size_t)s * 4 + q];
            f[k] = v ? 1.0f : 0.0f;
        }
#pragma unroll
        for (int k = 0; k < 4; k++) {
            accB[0] += f[k] * lo16(hi[k].x); accB[1] += f[k] * hi16(hi[k].x);
            accB[2] += f[k] * lo16(hi[k].y); accB[3] += f[k] * hi16(hi[k].y);
            accB[4] += f[k] * lo16(hi[k].z); accB[5] += f[k] * hi16(hi[k].z);
            accB[6] += f[k] * lo16(hi[k].w); accB[7] += f[k] * hi16(hi[k].w);
        }
        e4 = e4n;
    }
    if (w != 0) {
#pragma unroll
        for (int j = 0; j < 8; j++) redB[w - 1][lane][j] = accB[j];
        redS[w - 1][lane] = sfix;
    }
    __syncthreads();
    if (w != 0) return;
#pragma unroll
    for (int p = 0; p < 3; p++) {
#pragma unroll
        for (int j = 0; j < 8; j++) accB[j] += redB[p][lane][j];
        sfix += redS[p][lane];
    }

    // sattr: layer0 computes from fixed-point payload, later layers load
    float satv;
    if (layer0) {
        satv = (float)(int)sfix * (1.0f / FIXS) - 8.0f * (float)dg;
        if (lane < 16) sattr[nodeBase + lane] = satv;
    } else {
        satv = sattr[m];
    }

    // A-fragments: af0 straight from aggLO (already bf16 in fragment layout)
    bf16x8 af0 = *(const bf16x8*)&aggLO[(size_t)m * 4 + q];
    bf16x8 af1;
#pragma unroll
    for (int j = 0; j < 8; j++) af1[j] = (short)f2bf(accB[j]);

    // B-fragments: B[k][n]: n=lane&15, k=q*8+j.  W1 row-major [64][64].
    int q8 = q * 8;
    f32x4 c[4];
#pragma unroll
    for (int nt = 0; nt < 4; nt++) {
        bf16x8 b0, b1;
#pragma unroll
        for (int j = 0; j < 8; j++) {
            b0[j] = (short)f2bf(W1[(q8 + j) * HID + nt * 16 + n15]);
            b1[j] = (short)f2bf(W1[(32 + q8 + j) * HID + nt * 16 + n15]);
        }
        f32x4 z = {0.f, 0.f, 0.f, 0.f};
        c[nt] = __builtin_amdgcn_mfma_f32_16x16x32_bf16(af0, b0, z, 0, 0, 0);
        c[nt] = __builtin_amdgcn_mfma_f32_16x16x32_bf16(af1, b1, c[nt], 0, 0, 0);
    }

    // epilogue: C/D col=lane&15, row=q*4+reg
    float dgown = (float)dg;
    float sat[4], dgf[4];
#pragma unroll
    for (int r = 0; r < 4; r++) {
        int srcLane = q * 4 + r;
        sat[r] = __shfl(satv, srcLane);
        dgf[r] = __shfl(dgown, srcLane);
    }
#pragma unroll
    for (int nt = 0; nt < 4; nt++) {
        int col = nt * 16 + n15;
        float uc = uv_l[col], vc = uv_l[HID + col], bc = node_b_l[col];
#pragma unroll
        for (int r = 0; r < 4; r++) {
            int n = nodeBase + q * 4 + r;
            float val = c[nt][r] + sat[r] * uc + dgf[r] * vc + bc;
            val = val > 0.f ? val : 0.f;               // relu (leaky∘relu = id)
            if (out_f32) {
                out_f32[(size_t)n * HID + col] = val;
            } else {
                ushort_t* pl = (nt < 2) ? out_lo : out_hi;
                pl[(size_t)n * 32 + (col & 31)] = f2bf(val);
            }
        }
    }
}

// One block per graph: sum contiguous rows [gstart[g], gstart[g+1]), dot fc_w, write out[g].
__global__ __launch_bounds__(256) void pool_fc_kernel(
        const float* __restrict__ x, const int* __restrict__ gstart,
        const float* __restrict__ fc_w, const float* __restrict__ fc_b,
        float* __restrict__ out) {
    __shared__ float red[4][HID];
    int g = blockIdx.x;
    int lane = threadIdx.x & 63, w = threadIdx.x >> 6;
    int s = gstart[g], e = gstart[g + 1];
    float acc = 0.f;
    int r = s + w;
    for (; r + 12 < e; r += 16) {                    // 4 independent loads in flight
        float a0 = x[(size_t)(r     ) * HID + lane];
        float a1 = x[(size_t)(r +  4) * HID + lane];
        float a2 = x[(size_t)(r +  8) * HID + lane];
        float a3 = x[(size_t)(r + 12) * HID + lane];
        acc += a0 + a1 + a2 + a3;
    }
    for (; r < e; r += 4) acc += x[(size_t)r * HID + lane];
    red[w][lane] = acc;
    __syncthreads();
    if (w != 0) return;
    acc = red[0][lane] + red[1][lane] + red[2][lane] + red[3][lane];
    float dot = acc * fc_w[lane];
    for (int off = 32; off > 0; off >>= 1) dot += __shfl_down(dot, off);
    if (lane == 0) {
        float cntf = (float)(e - s);
        if (cntf < 1.f) cntf = 1.f;
        out[g] = dot / cntf + fc_b[0];
    }
}

extern "C" void kernel_launch(void* const* d_in, const int* in_sizes, int n_in,
                              void* d_out, int out_size, void* d_ws, size_t ws_size,
                              hipStream_t stream) {
    const float* x_in      = (const float*)d_in[0];
    const float* edge_attr = (const float*)d_in[1];
    const float* edge_w    = (const float*)d_in[2];
    const float* edge_b    = (const float*)d_in[3];
    const float* node_w    = (const float*)d_in[4];
    const float* node_b    = (const float*)d_in[5];
    const float* fc_w      = (const float*)d_in[6];
    const float* fc_b      = (const float*)d_in[7];
    const int*   edge_index= (const int*)d_in[8];
    const int*   batch     = (const int*)d_in[9];
    float* out = (float*)d_out;

    // workspace: loA|hiA|loB|hiB|aggLO (bf16 [N][32] each) | xA | ell | cnt | gstart | sattr | uv
    ushort_t* loA  = (ushort_t*)d_ws;
    ushort_t* hiA  = loA + (size_t)N_NODES * 32;
    ushort_t* loB  = hiA + (size_t)N_NODES * 32;
    ushort_t* hiB  = loB + (size_t)N_NODES * 32;
    ushort_t* agl  = hiB + (size_t)N_NODES * 32;
    float*    xA   = (float*)(agl + (size_t)N_NODES * 32);
    u32*      ell  = (u32*)(xA + (size_t)N_NODES * HID);
    int*      cnt  = (int*)(ell + (size_t)N_NODES * MAXDEG);    // ---- zeroed, stride 32 ----
    int*      gstart = cnt + (size_t)N_NODES * CNTSTRIDE;       // [N_GRAPHS+1], fully written
    float*    sattr  = (float*)(gstart + N_GRAPHS + 1);
    float*    uv     = sattr + N_NODES;
    // total ~48.3 MB

    const int* src = edge_index;            // edge_index[0]
    const int* dst = edge_index + N_EDGES;  // edge_index[1]

    hipMemsetAsync(cnt, 0, (size_t)N_NODES * CNTSTRIDE * sizeof(int), stream);

    const int EB  = (N_EDGES + 255) / 256;            // 3125 (1 edge/thread)
    const int CVT = (N_NODES * HID / 8 + 255) / 256;  // 1563
    const int GB  = (N_NODES + 255) / 256;            // 196
    edge_cvt_uv_kernel<<<EB + CVT + GB + 1, 256, 0, stream>>>(
        src, dst, edge_attr, cnt, ell, x_in, (uint4*)loA, (uint4*)hiA, batch, gstart,
        edge_w, edge_b, node_w, uv, EB, CVT, GB);

    const int AGG_BLOCKS = N_NODES / 16;            // 3125 groups
    // layer 0: planes A -> planes B
    agg_lo_kernel<<<AGG_BLOCKS, 256, 0, stream>>>((uint4*)loA, ell, cnt, (uint4*)agl);
    agg_hi_mfma_kernel<<<AGG_BLOCKS, 256, 0, stream>>>(
        (uint4*)hiA, (uint4*)agl, ell, cnt, node_w, node_b, uv, sattr, 1,
        loB, hiB, nullptr);
    // layer 1: planes B -> planes A
    agg_lo_kernel<<<AGG_BLOCKS, 256, 0, stream>>>((uint4*)loB, ell, cnt, (uint4*)agl);
    agg_hi_mfma_kernel<<<AGG_BLOCKS, 256, 0, stream>>>(
        (uint4*)hiB, (uint4*)agl, ell, cnt, node_w + (size_t)2 * HID * HID,
        node_b + HID, uv + 2 * HID, sattr, 0, loA, hiA, nullptr);
    // layer 2: planes A -> xA (fp32)
    agg_lo_kernel<<<AGG_BLOCKS, 256, 0, stream>>>((uint4*)loA, ell, cnt, (uint4*)agl);
    agg_hi_mfma_kernel<<<AGG_BLOCKS, 256, 0, stream>>>(
        (uint4*)hiA, (uint4*)agl, ell, cnt, node_w + (size_t)4 * HID * HID,
        node_b + 2 * HID, uv + 4 * HID, sattr, 0, nullptr, nullptr, xA);

    pool_fc_kernel<<<N_GRAPHS, 256, 0, stream>>>(xA, gstart, fc_w, fc_b, out);
}

// Round 4
// 189.333 us; speedup vs baseline: 1.2217x; 1.2217x over previous
//
#include <hip/hip_runtime.h>

#define N_NODES 50000
#define N_EDGES 800000
#define HID 64
#define N_LAYERS 3
#define N_GRAPHS 64
#define MAXDEG 64
#define FIXS 4096.0f
#define CNTSTRIDE 32   // 1 counter per 128B line (kept from round 2)

typedef unsigned int u32;
typedef unsigned short ushort_t;
typedef short bf16x8 __attribute__((ext_vector_type(8)));
typedef float f32x4 __attribute__((ext_vector_type(4)));

__device__ __forceinline__ ushort_t f2bf(float f) {
    unsigned int u = __builtin_bit_cast(unsigned int, f);
    unsigned int r = u + 0x7fffu + ((u >> 16) & 1u);   // RNE
    return (ushort_t)(r >> 16);
}
__device__ __forceinline__ float lo16(u32 u) { return __builtin_bit_cast(float, u << 16); }
__device__ __forceinline__ float hi16(u32 u) { return __builtin_bit_cast(float, u & 0xffff0000u); }

// Fused: [0,EB) edge pass (1 edge/thread); [EB,EB+CVT) x_in->bf16 cvt; [.., +GB) batch
// boundary scan; last block: uv fold + out init (out[g] = fc_b).
__global__ __launch_bounds__(256) void edge_cvt_uv_kernel(
        const int* __restrict__ src, const int* __restrict__ dst,
        const float* __restrict__ ea,
        int* __restrict__ cnt, u32* __restrict__ ell,
        const float* __restrict__ x_in, uint4* __restrict__ xbf0,
        const int* __restrict__ batch, int* __restrict__ gstart,
        const float* __restrict__ edge_w, const float* __restrict__ edge_b,
        const float* __restrict__ node_w, float* __restrict__ uv,
        const float* __restrict__ fc_b, float* __restrict__ out,
        int edgeBlocks, int cvtBlocks, int gbBlocks) {
    int t = threadIdx.x;
    int b = (int)blockIdx.x;
    if (b < edgeBlocks) {
        int e = b * 256 + t;
        if (e >= N_EDGES) return;
        int d = dst[e];
        float fv = (ea[e] + 8.0f) * FIXS;          // ea~N(0,1): in (0, 65536)
        fv = fminf(fmaxf(fv, 0.0f), 65535.0f);
        u32 fx = __float2uint_rn(fv);
        int pos = atomicAdd(&cnt[(size_t)d * CNTSTRIDE], 1);
        if (pos < MAXDEG) ell[((size_t)d << 6) + pos] = (u32)src[e] | (fx << 16);
        return;
    }
    if (b < edgeBlocks + cvtBlocks) {              // x_in -> bf16 (natural order)
        int i = (b - edgeBlocks) * 256 + t;        // one thread = 8 floats
        if (i < N_NODES * HID / 8) {
            const float4* p = (const float4*)(x_in + (size_t)i * 8);
            float4 a = p[0], c = p[1];
            uint4 o;
            o.x = (u32)f2bf(a.x) | ((u32)f2bf(a.y) << 16);
            o.y = (u32)f2bf(a.z) | ((u32)f2bf(a.w) << 16);
            o.z = (u32)f2bf(c.x) | ((u32)f2bf(c.y) << 16);
            o.w = (u32)f2bf(c.z) | ((u32)f2bf(c.w) << 16);
            xbf0[i] = o;
        }
        return;
    }
    if (b < edgeBlocks + cvtBlocks + gbBlocks) {   // graph boundary scan (batch sorted)
        int i = (b - edgeBlocks - cvtBlocks) * 256 + t;
        if (i >= N_NODES) return;
        int bi = batch[i];
        if (i == 0) {
            for (int g = 0; g <= bi; g++) gstart[g] = 0;
        } else {
            int bp = batch[i - 1];
            for (int g = bp + 1; g <= bi; g++) gstart[g] = i;
        }
        if (i == N_NODES - 1) {
            for (int g = bi + 1; g <= N_GRAPHS; g++) gstart[g] = N_NODES;
        }
        return;
    }
    // uv fold + out init
    if (t >= 192) {                                 // N_LAYERS*HID == 192
        if (t < 192 + N_GRAPHS) out[t - 192] = fc_b[0];
        return;
    }
    int l = t >> 6, hp = t & 63;
    const float* w2 = node_w + l * 2 * HID * HID + HID * HID + hp;
    float u = 0.f, v = 0.f;
    for (int h = 0; h < HID; h++) {
        float w = w2[h * HID];
        u += edge_w[l * HID + h] * w;
        v += edge_b[l * HID + h] * w;
    }
    uv[l * 2 * HID + hp]       = u;
    uv[l * 2 * HID + HID + hp] = v;
}

// Agg v2: 16 nodes per 256-thread block. Gather phase uses 8-lanes-per-node so each
// edge's full 128B row is ONE full-line request (halves request count vs 2x64B —
// theory: per-CU request-queue-slot limited). Wave pair {0,1} owns nodes 0-7,
// {2,3} owns nodes 8-15; K-split 2 within a pair. LDS remap to MFMA (q,n15) layout;
// MFMA + epilogue identical to the verified round-2 kernel.
__global__ __launch_bounds__(256) void agg_mfma_kernel(
        const ushort_t* __restrict__ xbf, const u32* __restrict__ ell,
        const int* __restrict__ cnt,
        const float* __restrict__ W1, const float* __restrict__ node_b_l,
        const float* __restrict__ uv_l, float* __restrict__ sattr,
        int layer0, ushort_t* __restrict__ out_bf, float* __restrict__ out_f32) {
    __shared__ float red[4][64][9];   // [wave][lane][feat]; stride 9 -> <=2-way on writes
    __shared__ u32   redS[4][8];
    int lane = threadIdx.x & 63;
    int w = threadIdx.x >> 6;             // 0..3
    int nodeBase = blockIdx.x * 16;
    int oct = lane & 7, n8 = lane >> 3;   // 8 lanes per node
    int pairSel = w >> 1;                 // node group: 0 -> nodes 0-7, 1 -> 8-15
    int kslice = w & 1;                   // K-split 2 within the pair

    int m = nodeBase + pairSel * 8 + n8;
    int dg = cnt[(size_t)m * CNTSTRIDE]; if (dg > MAXDEG) dg = MAXDEG;
    int mx = dg;
#pragma unroll
    for (int off = 8; off < 64; off <<= 1) {       // max over the wave's 8 nodes
        int o = __shfl_xor(mx, off);
        mx = o > mx ? o : mx;
    }

    const uint4* erow4 = (const uint4*)(ell + ((size_t)m << 6));
    const uint4* xrows = (const uint4*)xbf;        // 8 uint4 per 128B node row
    float accC[8] = {0,0,0,0,0,0,0,0};             // features oct*8 .. oct*8+7
    u32 sfix = 0;
    int base = kslice * 4;
    uint4 e4 = {0, 0, 0, 0};
    if (base < mx) e4 = erow4[base >> 2];          // wave-uniform condition
    for (; base < mx; base += 8) {
        int nbase = base + 8;
        uint4 e4n = {0, 0, 0, 0};
        if (nbase < mx) e4n = erow4[nbase >> 2];   // prefetch next chunk
        u32 ee[4] = {e4.x, e4.y, e4.z, e4.w};
        uint4 rw[4];
        float f[4];
#pragma unroll
        for (int k = 0; k < 4; k++) {              // issue all 4 full-line loads first
            bool v = (base + k) < dg;
            sfix += (v && oct == 0) ? (ee[k] >> 16) : 0u;
            int s = v ? (int)(ee[k] & 0xffffu) : 0;
            rw[k] = xrows[(size_t)s * 8 + oct];    // 8 lanes x 16B = one 128B line
            f[k] = v ? 1.0f : 0.0f;
        }
#pragma unroll
        for (int k = 0; k < 4; k++) {              // consume
            accC[0] += f[k] * lo16(rw[k].x); accC[1] += f[k] * hi16(rw[k].x);
            accC[2] += f[k] * lo16(rw[k].y); accC[3] += f[k] * hi16(rw[k].y);
            accC[4] += f[k] * lo16(rw[k].z); accC[5] += f[k] * hi16(rw[k].z);
            accC[6] += f[k] * lo16(rw[k].w); accC[7] += f[k] * hi16(rw[k].w);
        }
        e4 = e4n;
    }

#pragma unroll
    for (int j = 0; j < 8; j++) red[w][lane][j] = accC[j];
    if (oct == 0) redS[w][n8] = sfix;
    __syncthreads();
    if (w != 0) return;

    // remap oct-layout partials -> MFMA (q, n15) layout, combining the K-split pair
    int q = lane >> 4, n15 = lane & 15;
    int w0 = (n15 >> 3) * 2;               // wave pair holding node n15
    int h8 = (n15 & 7) * 8;
    float accA[8], accB[8];
#pragma unroll
    for (int j = 0; j < 8; j++) {
        accA[j] = red[w0][h8 + q][j]     + red[w0 + 1][h8 + q][j];       // feats 8q+j
        accB[j] = red[w0][h8 + 4 + q][j] + red[w0 + 1][h8 + 4 + q][j];   // feats 32+8q+j
    }
    u32 sfix2 = redS[w0][n15 & 7] + redS[w0 + 1][n15 & 7];
    int m2 = nodeBase + n15;
    int dg2 = cnt[(size_t)m2 * CNTSTRIDE]; if (dg2 > MAXDEG) dg2 = MAXDEG;

    // sattr: layer0 computes from fixed-point payload, later layers load
    float satv;
    if (layer0) {
        satv = (float)(int)sfix2 * (1.0f / FIXS) - 8.0f * (float)dg2;
        if (lane < 16) sattr[m2] = satv;   // lane<16 => q==0, n15=lane
    } else {
        satv = sattr[m2];
    }

    // A-fragments: A[m=lane&15][k=q*8+j]
    bf16x8 af0, af1;
#pragma unroll
    for (int j = 0; j < 8; j++) {
        af0[j] = (short)f2bf(accA[j]);
        af1[j] = (short)f2bf(accB[j]);
    }

    // B-fragments: B[k][n]: n=lane&15, k=q*8+j.  W1 row-major [64][64].
    int q8 = q * 8;
    f32x4 c[4];
#pragma unroll
    for (int nt = 0; nt < 4; nt++) {
        bf16x8 b0, b1;
#pragma unroll
        for (int j = 0; j < 8; j++) {
            b0[j] = (short)f2bf(W1[(q8 + j) * HID + nt * 16 + n15]);
            b1[j] = (short)f2bf(W1[(32 + q8 + j) * HID + nt * 16 + n15]);
        }
        f32x4 z = {0.f, 0.f, 0.f, 0.f};
        c[nt] = __builtin_amdgcn_mfma_f32_16x16x32_bf16(af0, b0, z, 0, 0, 0);
        c[nt] = __builtin_amdgcn_mfma_f32_16x16x32_bf16(af1, b1, c[nt], 0, 0, 0);
    }

    // epilogue: C/D col=lane&15, row=q*4+reg
    float dgown = (float)dg2;
    float sat[4], dgf[4];
#pragma unroll
    for (int r = 0; r < 4; r++) {
        int srcLane = q * 4 + r;
        sat[r] = __shfl(satv, srcLane);
        dgf[r] = __shfl(dgown, srcLane);
    }
#pragma unroll
    for (int nt = 0; nt < 4; nt++) {
        int col = nt * 16 + n15;
        float uc = uv_l[col], vc = uv_l[HID + col], bc = node_b_l[col];
#pragma unroll
        for (int r = 0; r < 4; r++) {
            int n = nodeBase + q * 4 + r;
            float val = c[nt][r] + sat[r] * uc + dgf[r] * vc + bc;
            val = val > 0.f ? val : 0.f;               // relu (leaky∘relu = id)
            if (out_bf) out_bf[(size_t)n * HID + col] = f2bf(val);
            else        out_f32[(size_t)n * HID + col] = val;
        }
    }
}

// Pool v2: 8 blocks per graph (512 blocks total — old 64-block version left 75% of CUs
// idle). Each block partial-sums an interleaved row slice, dots fc_w, atomicAdd's the
// slice contribution / count into out[g] (pre-initialized to fc_b).
__global__ __launch_bounds__(256) void pool_fc_kernel(
        const float* __restrict__ x, const int* __restrict__ gstart,
        const float* __restrict__ fc_w, float* __restrict__ out) {
    __shared__ float red[4][HID];
    int g = blockIdx.x >> 3, s8 = blockIdx.x & 7;
    int lane = threadIdx.x & 63, w = threadIdx.x >> 6;
    int s = gstart[g], e = gstart[g + 1];
    float acc = 0.f;
    int r = s + s8 * 4 + w;                         // residues s8*4+w mod 32
    for (; r + 96 < e; r += 128) {                  // 4 independent loads in flight
        float a0 = x[(size_t)(r     ) * HID + lane];
        float a1 = x[(size_t)(r + 32) * HID + lane];
        float a2 = x[(size_t)(r + 64) * HID + lane];
        float a3 = x[(size_t)(r + 96) * HID + lane];
        acc += a0 + a1 + a2 + a3;
    }
    for (; r < e; r += 32) acc += x[(size_t)r * HID + lane];
    red[w][lane] = acc;
    __syncthreads();
    if (w != 0) return;
    acc = red[0][lane] + red[1][lane] + red[2][lane] + red[3][lane];
    float dot = acc * fc_w[lane];
    for (int off = 32; off > 0; off >>= 1) dot += __shfl_down(dot, off);
    if (lane == 0) {
        float cntf = (float)(e - s);
        if (cntf < 1.f) cntf = 1.f;
        atomicAdd(&out[g], dot / cntf);
    }
}

extern "C" void kernel_launch(void* const* d_in, const int* in_sizes, int n_in,
                              void* d_out, int out_size, void* d_ws, size_t ws_size,
                              hipStream_t stream) {
    const float* x_in      = (const float*)d_in[0];
    const float* edge_attr = (const float*)d_in[1];
    const float* edge_w    = (const float*)d_in[2];
    const float* edge_b    = (const float*)d_in[3];
    const float* node_w    = (const float*)d_in[4];
    const float* node_b    = (const float*)d_in[5];
    const float* fc_w      = (const float*)d_in[6];
    const float* fc_b      = (const float*)d_in[7];
    const int*   edge_index= (const int*)d_in[8];
    const int*   batch     = (const int*)d_in[9];
    float* out = (float*)d_out;

    // workspace: xbf0 | xbf1 | xA | ell | cnt (padded, zeroed) | gstart | sattr | uv
    ushort_t* xbf0  = (ushort_t*)d_ws;
    ushort_t* xbf1  = xbf0 + (size_t)N_NODES * HID;
    float*    xA    = (float*)(xbf1 + (size_t)N_NODES * HID);
    u32*      ell   = (u32*)(xA + (size_t)N_NODES * HID);
    int*      cnt   = (int*)(ell + (size_t)N_NODES * MAXDEG);   // ---- zeroed, stride 32 ----
    int*      gstart= cnt + (size_t)N_NODES * CNTSTRIDE;        // [N_GRAPHS+1], fully written
    float*    sattr = (float*)(gstart + N_GRAPHS + 1);
    float*    uv    = sattr + N_NODES;
    // total ~45 MB

    const int* src = edge_index;            // edge_index[0]
    const int* dst = edge_index + N_EDGES;  // edge_index[1]

    hipMemsetAsync(cnt, 0, (size_t)N_NODES * CNTSTRIDE * sizeof(int), stream);

    const int EB  = (N_EDGES + 255) / 256;            // 3125 (1 edge/thread)
    const int CVT = (N_NODES * HID / 8 + 255) / 256;  // 1563
    const int GB  = (N_NODES + 255) / 256;            // 196
    edge_cvt_uv_kernel<<<EB + CVT + GB + 1, 256, 0, stream>>>(
        src, dst, edge_attr, cnt, ell, x_in, (uint4*)xbf0, batch, gstart,
        edge_w, edge_b, node_w, uv, fc_b, out, EB, CVT, GB);

    // layers: xbf0 -> xbf1 (bf16) -> xbf0 (bf16) -> xA (fp32)
    const int AGG_BLOCKS = N_NODES / 16;            // 3125 groups, 1 per 256-thr block
    agg_mfma_kernel<<<AGG_BLOCKS, 256, 0, stream>>>(
        xbf0, ell, cnt, node_w, node_b, uv, sattr, 1, xbf1, nullptr);
    agg_mfma_kernel<<<AGG_BLOCKS, 256, 0, stream>>>(
        xbf1, ell, cnt, node_w + (size_t)2 * HID * HID, node_b + HID, uv + 2 * HID,
        sattr, 0, xbf0, nullptr);
    agg_mfma_kernel<<<AGG_BLOCKS, 256, 0, stream>>>(
        xbf0, ell, cnt, node_w + (size_t)4 * HID * HID, node_b + 2 * HID, uv + 4 * HID,
        sattr, 0, nullptr, xA);

    pool_fc_kernel<<<N_GRAPHS * 8, 256, 0, stream>>>(xA, gstart, fc_w, out);
}